// Round 19
// baseline (42.654 us; speedup 1.0000x reference)
//
#include <hip/hip_runtime.h>

typedef float f32x4 __attribute__((ext_vector_type(4)));

// out[b][v][p][i][s] = shell[s]*sh[i] / norm[b][l(i)][s]
// B=8 V=2048 P=32 I=16 S=4, monoms=20
// k1 REDESIGN: A1 stage m[20]+shl2[4] per point -> LDS[256][28];
//              A2 thread=(i,pg): Y row in 20 VGPRs, 16 pts x {6 b128 + 25 VALU},
//              shfl_xor(16) fold -> l2[u][i][s]; phases C/D as before.
// k3: EXACT R16 keeper (36.97us baseline).

__device__ __forceinline__ void compute_monoms(float nx, float ny, float nz, float* m) {
    float zp2 = nz*nz, zp3 = zp2*nz;
    float yp2 = ny*ny, yp3 = yp2*ny;
    float xp2 = nx*nx, xp3 = xp2*nx;
    m[0]=1.0f;  m[1]=nz;       m[2]=zp2;      m[3]=zp3;
    m[4]=ny;    m[5]=ny*nz;    m[6]=ny*zp2;
    m[7]=yp2;   m[8]=yp2*nz;   m[9]=yp3;
    m[10]=nx;   m[11]=nx*nz;   m[12]=nx*zp2;
    m[13]=nx*ny; m[14]=nx*ny*nz; m[15]=nx*yp2;
    m[16]=xp2;  m[17]=xp2*nz;  m[18]=xp2*ny;
    m[19]=xp3;
}

__device__ __forceinline__ void compute_shells(float dist, float* sl) {
    const float B1 = 32.0f/3.0f, B2 = 64.0f/3.0f, B3 = 32.0f;
    const float C1 = -16.0f/9.0f, C2 = -64.0f/9.0f, C3 = -16.0f;
    float nd2 = -16.0f * dist * dist;
    sl[0] = __expf(nd2);
    sl[1] = __expf(fmaf(B1, dist, nd2 + C1));
    sl[2] = __expf(fmaf(B2, dist, nd2 + C2));
    sl[3] = __expf(fmaf(B3, dist, nd2 + C3));
    float den = sl[0] + sl[1] + sl[2] + sl[3];
    float r = 1.0f / fmaxf(den, 1e-6f);
    float mask = (dist <= 1.0f) ? r : 0.0f;
#pragma unroll
    for (int s = 0; s < 4; ++s) sl[s] *= mask;
}

// ---------------- K1: 2048 blocks, 8 units; Y-in-VGPR dot ----------------
__global__ __launch_bounds__(256) void sh_k1(const float* __restrict__ patches,
                                             const float* __restrict__ Y,
                                             float* __restrict__ partials) {
    __shared__ float mrow[256][28];    // [0..19]=m, [20..23]=shl^2; stride 28 = perfect bank tile
    __shared__ float l2_lds[8][16][4];
    __shared__ float red[8][16];

    const int tid  = threadIdx.x;
    const int wv   = tid >> 6;
    const int lane = tid & 63;

    // ---- A1: per-point monoms + shl^2 -> LDS (global point = blk*256 + tid) ----
    {
        const size_t ptg = (size_t)blockIdx.x*256 + tid;
        const float* pp = patches + ptg*3;
        float x = pp[0], y = pp[1], z = pp[2];
        float dist = sqrtf(x*x + y*y + z*z);
        float inv  = 1.0f / fmaxf(dist, 1e-6f);
        float nx = -x*inv, ny = -y*inv, nz = -z*inv;
        float m[20];
        compute_monoms(nx, ny, nz, m);
        float sl[4];
        compute_shells(dist, sl);
#pragma unroll
        for (int k = 0; k < 5; ++k)
            *(f32x4*)&mrow[tid][k*4] = f32x4{ m[k*4+0], m[k*4+1], m[k*4+2], m[k*4+3] };
        *(f32x4*)&mrow[tid][20] = f32x4{ sl[0]*sl[0], sl[1]*sl[1], sl[2]*sl[2], sl[3]*sl[3] };
    }
    __syncthreads();

    // ---- A2: thread (i, pg); Y row i in VGPRs; sweep 16 points of this wave ----
    const int i  = lane & 15;
    const int pg = lane >> 4;            // 0..3
    {
        const float4* Y4 = (const float4*)Y;
        float yr[20];
#pragma unroll
        for (int q = 0; q < 5; ++q) {
            float4 t = Y4[i*5 + q];
            yr[q*4+0]=t.x; yr[q*4+1]=t.y; yr[q*4+2]=t.z; yr[q*4+3]=t.w;
        }
        f32x4 acc = { 0.f, 0.f, 0.f, 0.f };
        const int rowbase = wv*64 + pg*16;
#pragma unroll
        for (int k = 0; k < 16; ++k) {
            const float* mr = &mrow[rowbase + k][0];
            f32x4 m0 = *(const f32x4*)&mr[0];
            f32x4 m1 = *(const f32x4*)&mr[4];
            f32x4 m2 = *(const f32x4*)&mr[8];
            f32x4 m3 = *(const f32x4*)&mr[12];
            f32x4 m4 = *(const f32x4*)&mr[16];
            f32x4 w  = *(const f32x4*)&mr[20];
            float sh = 0.f;
            sh = fmaf(yr[0],  m0.x, sh); sh = fmaf(yr[1],  m0.y, sh);
            sh = fmaf(yr[2],  m0.z, sh); sh = fmaf(yr[3],  m0.w, sh);
            sh = fmaf(yr[4],  m1.x, sh); sh = fmaf(yr[5],  m1.y, sh);
            sh = fmaf(yr[6],  m1.z, sh); sh = fmaf(yr[7],  m1.w, sh);
            sh = fmaf(yr[8],  m2.x, sh); sh = fmaf(yr[9],  m2.y, sh);
            sh = fmaf(yr[10], m2.z, sh); sh = fmaf(yr[11], m2.w, sh);
            sh = fmaf(yr[12], m3.x, sh); sh = fmaf(yr[13], m3.y, sh);
            sh = fmaf(yr[14], m3.z, sh); sh = fmaf(yr[15], m3.w, sh);
            sh = fmaf(yr[16], m4.x, sh); sh = fmaf(yr[17], m4.y, sh);
            sh = fmaf(yr[18], m4.z, sh); sh = fmaf(yr[19], m4.w, sh);
            float sh2 = sh * sh;
            acc.x = fmaf(sh2, w.x, acc.x);
            acc.y = fmaf(sh2, w.y, acc.y);
            acc.z = fmaf(sh2, w.z, acc.z);
            acc.w = fmaf(sh2, w.w, acc.w);
        }
        // fold pgrp pairs (0,1) and (2,3): unit = wv*2 + (lane>>5)
        acc.x += __shfl_xor(acc.x, 16);
        acc.y += __shfl_xor(acc.y, 16);
        acc.z += __shfl_xor(acc.z, 16);
        acc.w += __shfl_xor(acc.w, 16);
        if (((lane >> 4) & 1) == 0) {
            const int u = wv*2 + (lane >> 5);
            *(f32x4*)&l2_lds[u][i][0] = acc;
        }
    }
    __syncthreads();

    // ---- phase C: group-sum over i within l, sqrt -> red ----
    if (lane < 32) {
        const int h2 = lane >> 4;
        const int c  = lane & 15;            // c = l*4 + s
        const int l  = c >> 2, sc = c & 3;
        const int uc = wv*2 + h2;
        const int start = l*l, cnt = 2*l + 1;
        float acc = 0.f;
        for (int t = 0; t < cnt; ++t) acc += l2_lds[uc][start + t][sc];
        red[uc][c] = sqrtf(acc);
    }
    __syncthreads();
    if (tid < 16) {
        float s2 = 0.f;
#pragma unroll
        for (int uc = 0; uc < 8; ++uc) s2 += red[uc][tid];
        partials[blockIdx.x*16 + tid] = s2;   // deterministic, no atomics
    }
}

// ---------------- K3: EXACT R16 keeper ----------------
__global__ __launch_bounds__(256) void sh_k3(const float* __restrict__ patches,
                                             const float* __restrict__ Y,
                                             const float* __restrict__ partials,
                                             f32x4* __restrict__ out) {
    __shared__ float mon[256][12];     // [0..2]=n, [4..7]=sl, stride 12
    __shared__ float pr[16][17];
    __shared__ float rcp_lds[16];

    const int tid = threadIdx.x;
    const int blk = blockIdx.x;        // 0..2047, 256 blocks per batch
    const int bb  = blk >> 8;          // batch

    const int ch = tid & 15, r0 = tid >> 4;
    float pl[16];
#pragma unroll
    for (int r = 0; r < 16; ++r)
        pl[r] = partials[((size_t)bb*256 + r0 + r*16)*16 + ch];

    {
        const size_t ptg = (size_t)blk*256 + tid;
        const float* pp = patches + ptg*3;
        float x = pp[0], y = pp[1], z = pp[2];
        float dist = sqrtf(x*x + y*y + z*z);
        float inv  = 1.0f / fmaxf(dist, 1e-6f);
        float sl[4];
        compute_shells(dist, sl);
        f32x4 n4 = { -x*inv, -y*inv, -z*inv, 0.f };
        f32x4 s4 = { sl[0], sl[1], sl[2], sl[3] };
        *(f32x4*)&mon[tid][0] = n4;
        *(f32x4*)&mon[tid][4] = s4;
    }
    {
        float a = 0.f;
#pragma unroll
        for (int r = 0; r < 16; ++r) a += pl[r];
        pr[r0][ch] = a;
    }
    __syncthreads();
    if (tid < 16) {
        float s = 0.f;
#pragma unroll
        for (int r = 0; r < 16; ++r) s += pr[r][tid];
        float meanv = s * (1.0f/2048.0f);
        rcp_lds[tid] = 1.0f / fmaxf(meanv, 1e-8f);
    }
    __syncthreads();

    const int i    = tid & 15;
    const int pgrp = tid >> 4;

    const float4* Y4 = (const float4*)Y;
    float yr[20];
#pragma unroll
    for (int q = 0; q < 5; ++q) {
        float4 t = Y4[i*5 + q];
        yr[q*4+0]=t.x; yr[q*4+1]=t.y; yr[q*4+2]=t.z; yr[q*4+3]=t.w;
    }
    const int l = (i == 0) ? 0 : ((i < 4) ? 1 : ((i < 9) ? 2 : 3));
    const float rc0=rcp_lds[l*4+0], rc1=rcp_lds[l*4+1], rc2=rcp_lds[l*4+2], rc3=rcp_lds[l*4+3];

#pragma unroll 2
    for (int it2 = 0; it2 < 16; ++it2) {
        const int r = it2*16 + pgrp;
        f32x4 n4 = *(const f32x4*)&mon[r][0];
        f32x4 s4 = *(const f32x4*)&mon[r][4];

        float m[20];
        compute_monoms(n4.x, n4.y, n4.z, m);

        float sh = 0.f;
#pragma unroll
        for (int j = 0; j < 20; ++j)
            sh = fmaf(yr[j], m[j], sh);

        const size_t pt = (size_t)blk*256 + r;
        f32x4 o;
        o.x = sh*s4.x*rc0;
        o.y = sh*s4.y*rc1;
        o.z = sh*s4.z*rc2;
        o.w = sh*s4.w*rc3;
        out[pt*16 + i] = o;             // plain store (R16 keeper)
    }
}

extern "C" void kernel_launch(void* const* d_in, const int* in_sizes, int n_in,
                              void* d_out, int out_size, void* d_ws, size_t ws_size,
                              hipStream_t stream) {
    const float* patches = (const float*)d_in[0];   // 8*2048*32*3
    const float* Y       = (const float*)d_in[1];   // 16*20
    f32x4* out4 = (f32x4*)d_out;

    float* partials = (float*)d_ws;                 // 2048*16 floats = 128 KB

    sh_k1<<<2048, 256, 0, stream>>>(patches, Y, partials);
    sh_k3<<<2048, 256, 0, stream>>>(patches, Y, partials, out4);
}

// Round 20
// 42.356 us; speedup vs baseline: 1.0070x; 1.0070x over previous
//
#include <hip/hip_runtime.h>

typedef float f32x4 __attribute__((ext_vector_type(4)));

// out[b][v][p][i][s] = shell[s]*sh[i] / norm[b][l(i)][s]
// B=8 V=2048 P=32 I=16 S=4, monoms=20
// k1 REDESIGN: A1 stage m[20]+shl2[4] per point -> LDS[256][28];
//              A2 thread=(i,pg): Y row in 20 VGPRs, 16 pts x {6 b128 + 25 VALU},
//              shfl_xor(16) fold -> l2[u][i][s]; phases C/D as before.
// k3: EXACT R16 keeper (36.97us baseline).

__device__ __forceinline__ void compute_monoms(float nx, float ny, float nz, float* m) {
    float zp2 = nz*nz, zp3 = zp2*nz;
    float yp2 = ny*ny, yp3 = yp2*ny;
    float xp2 = nx*nx, xp3 = xp2*nx;
    m[0]=1.0f;  m[1]=nz;       m[2]=zp2;      m[3]=zp3;
    m[4]=ny;    m[5]=ny*nz;    m[6]=ny*zp2;
    m[7]=yp2;   m[8]=yp2*nz;   m[9]=yp3;
    m[10]=nx;   m[11]=nx*nz;   m[12]=nx*zp2;
    m[13]=nx*ny; m[14]=nx*ny*nz; m[15]=nx*yp2;
    m[16]=xp2;  m[17]=xp2*nz;  m[18]=xp2*ny;
    m[19]=xp3;
}

__device__ __forceinline__ void compute_shells(float dist, float* sl) {
    const float B1 = 32.0f/3.0f, B2 = 64.0f/3.0f, B3 = 32.0f;
    const float C1 = -16.0f/9.0f, C2 = -64.0f/9.0f, C3 = -16.0f;
    float nd2 = -16.0f * dist * dist;
    sl[0] = __expf(nd2);
    sl[1] = __expf(fmaf(B1, dist, nd2 + C1));
    sl[2] = __expf(fmaf(B2, dist, nd2 + C2));
    sl[3] = __expf(fmaf(B3, dist, nd2 + C3));
    float den = sl[0] + sl[1] + sl[2] + sl[3];
    float r = 1.0f / fmaxf(den, 1e-6f);
    float mask = (dist <= 1.0f) ? r : 0.0f;
#pragma unroll
    for (int s = 0; s < 4; ++s) sl[s] *= mask;
}

// ---------------- K1: 2048 blocks, 8 units; Y-in-VGPR dot ----------------
__global__ __launch_bounds__(256) void sh_k1(const float* __restrict__ patches,
                                             const float* __restrict__ Y,
                                             float* __restrict__ partials) {
    __shared__ float mrow[256][28];    // [0..19]=m, [20..23]=shl^2; stride 28 = perfect bank tile
    __shared__ float l2_lds[8][16][4];
    __shared__ float red[8][16];

    const int tid  = threadIdx.x;
    const int wv   = tid >> 6;
    const int lane = tid & 63;

    // ---- A1: per-point monoms + shl^2 -> LDS (global point = blk*256 + tid) ----
    {
        const size_t ptg = (size_t)blockIdx.x*256 + tid;
        const float* pp = patches + ptg*3;
        float x = pp[0], y = pp[1], z = pp[2];
        float dist = sqrtf(x*x + y*y + z*z);
        float inv  = 1.0f / fmaxf(dist, 1e-6f);
        float nx = -x*inv, ny = -y*inv, nz = -z*inv;
        float m[20];
        compute_monoms(nx, ny, nz, m);
        float sl[4];
        compute_shells(dist, sl);
#pragma unroll
        for (int k = 0; k < 5; ++k)
            *(f32x4*)&mrow[tid][k*4] = f32x4{ m[k*4+0], m[k*4+1], m[k*4+2], m[k*4+3] };
        *(f32x4*)&mrow[tid][20] = f32x4{ sl[0]*sl[0], sl[1]*sl[1], sl[2]*sl[2], sl[3]*sl[3] };
    }
    __syncthreads();

    // ---- A2: thread (i, pg); Y row i in VGPRs; sweep 16 points of this wave ----
    const int i  = lane & 15;
    const int pg = lane >> 4;            // 0..3
    {
        const float4* Y4 = (const float4*)Y;
        float yr[20];
#pragma unroll
        for (int q = 0; q < 5; ++q) {
            float4 t = Y4[i*5 + q];
            yr[q*4+0]=t.x; yr[q*4+1]=t.y; yr[q*4+2]=t.z; yr[q*4+3]=t.w;
        }
        f32x4 acc = { 0.f, 0.f, 0.f, 0.f };
        const int rowbase = wv*64 + pg*16;
#pragma unroll
        for (int k = 0; k < 16; ++k) {
            const float* mr = &mrow[rowbase + k][0];
            f32x4 m0 = *(const f32x4*)&mr[0];
            f32x4 m1 = *(const f32x4*)&mr[4];
            f32x4 m2 = *(const f32x4*)&mr[8];
            f32x4 m3 = *(const f32x4*)&mr[12];
            f32x4 m4 = *(const f32x4*)&mr[16];
            f32x4 w  = *(const f32x4*)&mr[20];
            float sh = 0.f;
            sh = fmaf(yr[0],  m0.x, sh); sh = fmaf(yr[1],  m0.y, sh);
            sh = fmaf(yr[2],  m0.z, sh); sh = fmaf(yr[3],  m0.w, sh);
            sh = fmaf(yr[4],  m1.x, sh); sh = fmaf(yr[5],  m1.y, sh);
            sh = fmaf(yr[6],  m1.z, sh); sh = fmaf(yr[7],  m1.w, sh);
            sh = fmaf(yr[8],  m2.x, sh); sh = fmaf(yr[9],  m2.y, sh);
            sh = fmaf(yr[10], m2.z, sh); sh = fmaf(yr[11], m2.w, sh);
            sh = fmaf(yr[12], m3.x, sh); sh = fmaf(yr[13], m3.y, sh);
            sh = fmaf(yr[14], m3.z, sh); sh = fmaf(yr[15], m3.w, sh);
            sh = fmaf(yr[16], m4.x, sh); sh = fmaf(yr[17], m4.y, sh);
            sh = fmaf(yr[18], m4.z, sh); sh = fmaf(yr[19], m4.w, sh);
            float sh2 = sh * sh;
            acc.x = fmaf(sh2, w.x, acc.x);
            acc.y = fmaf(sh2, w.y, acc.y);
            acc.z = fmaf(sh2, w.z, acc.z);
            acc.w = fmaf(sh2, w.w, acc.w);
        }
        // fold pgrp pairs (0,1) and (2,3): unit = wv*2 + (lane>>5)
        acc.x += __shfl_xor(acc.x, 16);
        acc.y += __shfl_xor(acc.y, 16);
        acc.z += __shfl_xor(acc.z, 16);
        acc.w += __shfl_xor(acc.w, 16);
        if (((lane >> 4) & 1) == 0) {
            const int u = wv*2 + (lane >> 5);
            *(f32x4*)&l2_lds[u][i][0] = acc;
        }
    }
    __syncthreads();

    // ---- phase C: group-sum over i within l, sqrt -> red ----
    if (lane < 32) {
        const int h2 = lane >> 4;
        const int c  = lane & 15;            // c = l*4 + s
        const int l  = c >> 2, sc = c & 3;
        const int uc = wv*2 + h2;
        const int start = l*l, cnt = 2*l + 1;
        float acc = 0.f;
        for (int t = 0; t < cnt; ++t) acc += l2_lds[uc][start + t][sc];
        red[uc][c] = sqrtf(acc);
    }
    __syncthreads();
    if (tid < 16) {
        float s2 = 0.f;
#pragma unroll
        for (int uc = 0; uc < 8; ++uc) s2 += red[uc][tid];
        partials[blockIdx.x*16 + tid] = s2;   // deterministic, no atomics
    }
}

// ---------------- K3: EXACT R16 keeper ----------------
__global__ __launch_bounds__(256) void sh_k3(const float* __restrict__ patches,
                                             const float* __restrict__ Y,
                                             const float* __restrict__ partials,
                                             f32x4* __restrict__ out) {
    __shared__ float mon[256][12];     // [0..2]=n, [4..7]=sl, stride 12
    __shared__ float pr[16][17];
    __shared__ float rcp_lds[16];

    const int tid = threadIdx.x;
    const int blk = blockIdx.x;        // 0..2047, 256 blocks per batch
    const int bb  = blk >> 8;          // batch

    const int ch = tid & 15, r0 = tid >> 4;
    float pl[16];
#pragma unroll
    for (int r = 0; r < 16; ++r)
        pl[r] = partials[((size_t)bb*256 + r0 + r*16)*16 + ch];

    {
        const size_t ptg = (size_t)blk*256 + tid;
        const float* pp = patches + ptg*3;
        float x = pp[0], y = pp[1], z = pp[2];
        float dist = sqrtf(x*x + y*y + z*z);
        float inv  = 1.0f / fmaxf(dist, 1e-6f);
        float sl[4];
        compute_shells(dist, sl);
        f32x4 n4 = { -x*inv, -y*inv, -z*inv, 0.f };
        f32x4 s4 = { sl[0], sl[1], sl[2], sl[3] };
        *(f32x4*)&mon[tid][0] = n4;
        *(f32x4*)&mon[tid][4] = s4;
    }
    {
        float a = 0.f;
#pragma unroll
        for (int r = 0; r < 16; ++r) a += pl[r];
        pr[r0][ch] = a;
    }
    __syncthreads();
    if (tid < 16) {
        float s = 0.f;
#pragma unroll
        for (int r = 0; r < 16; ++r) s += pr[r][tid];
        float meanv = s * (1.0f/2048.0f);
        rcp_lds[tid] = 1.0f / fmaxf(meanv, 1e-8f);
    }
    __syncthreads();

    const int i    = tid & 15;
    const int pgrp = tid >> 4;

    const float4* Y4 = (const float4*)Y;
    float yr[20];
#pragma unroll
    for (int q = 0; q < 5; ++q) {
        float4 t = Y4[i*5 + q];
        yr[q*4+0]=t.x; yr[q*4+1]=t.y; yr[q*4+2]=t.z; yr[q*4+3]=t.w;
    }
    const int l = (i == 0) ? 0 : ((i < 4) ? 1 : ((i < 9) ? 2 : 3));
    const float rc0=rcp_lds[l*4+0], rc1=rcp_lds[l*4+1], rc2=rcp_lds[l*4+2], rc3=rcp_lds[l*4+3];

#pragma unroll 2
    for (int it2 = 0; it2 < 16; ++it2) {
        const int r = it2*16 + pgrp;
        f32x4 n4 = *(const f32x4*)&mon[r][0];
        f32x4 s4 = *(const f32x4*)&mon[r][4];

        float m[20];
        compute_monoms(n4.x, n4.y, n4.z, m);

        float sh = 0.f;
#pragma unroll
        for (int j = 0; j < 20; ++j)
            sh = fmaf(yr[j], m[j], sh);

        const size_t pt = (size_t)blk*256 + r;
        f32x4 o;
        o.x = sh*s4.x*rc0;
        o.y = sh*s4.y*rc1;
        o.z = sh*s4.z*rc2;
        o.w = sh*s4.w*rc3;
        out[pt*16 + i] = o;             // plain store (R16 keeper)
    }
}

extern "C" void kernel_launch(void* const* d_in, const int* in_sizes, int n_in,
                              void* d_out, int out_size, void* d_ws, size_t ws_size,
                              hipStream_t stream) {
    const float* patches = (const float*)d_in[0];   // 8*2048*32*3
    const float* Y       = (const float*)d_in[1];   // 16*20
    f32x4* out4 = (f32x4*)d_out;

    float* partials = (float*)d_ws;                 // 2048*16 floats = 128 KB

    sh_k1<<<2048, 256, 0, stream>>>(patches, Y, partials);
    sh_k3<<<2048, 256, 0, stream>>>(patches, Y, partials, out4);
}

// Round 21
// 39.830 us; speedup vs baseline: 1.0709x; 1.0634x over previous
//
#include <hip/hip_runtime.h>

typedef float f32x4 __attribute__((ext_vector_type(4)));

// out[b][v][p][i][s] = shell[s]*sh[i] / norm[b][l(i)][s]
// B=8 V=2048 P=32 I=16 S=4, monoms=20
// k1: EXACT R16 keeper (7.7us)
// k2: 128 blocks -> rcp_ws[128]  (removes per-k3-block reduction; 3rd node ~free per R9)
// k3: 8192 blocks x 64 points -> 4 execution waves; prologue = 16-float rcp load;
//     production 64 threads; consumption 4 iters of dense 1KB wave stores (plain).

__device__ __forceinline__ void compute_monoms(float nx, float ny, float nz, float* m) {
    float zp2 = nz*nz, zp3 = zp2*nz;
    float yp2 = ny*ny, yp3 = yp2*ny;
    float xp2 = nx*nx, xp3 = xp2*nx;
    m[0]=1.0f;  m[1]=nz;       m[2]=zp2;      m[3]=zp3;
    m[4]=ny;    m[5]=ny*nz;    m[6]=ny*zp2;
    m[7]=yp2;   m[8]=yp2*nz;   m[9]=yp3;
    m[10]=nx;   m[11]=nx*nz;   m[12]=nx*zp2;
    m[13]=nx*ny; m[14]=nx*ny*nz; m[15]=nx*yp2;
    m[16]=xp2;  m[17]=xp2*nz;  m[18]=xp2*ny;
    m[19]=xp3;
}

__device__ __forceinline__ void compute_shells(float dist, float* sl) {
    const float B1 = 32.0f/3.0f, B2 = 64.0f/3.0f, B3 = 32.0f;
    const float C1 = -16.0f/9.0f, C2 = -64.0f/9.0f, C3 = -16.0f;
    float nd2 = -16.0f * dist * dist;
    sl[0] = __expf(nd2);
    sl[1] = __expf(fmaf(B1, dist, nd2 + C1));
    sl[2] = __expf(fmaf(B2, dist, nd2 + C2));
    sl[3] = __expf(fmaf(B3, dist, nd2 + C3));
    float den = sl[0] + sl[1] + sl[2] + sl[3];
    float r = 1.0f / fmaxf(den, 1e-6f);
    float mask = (dist <= 1.0f) ? r : 0.0f;
#pragma unroll
    for (int s = 0; s < 4; ++s) sl[s] *= mask;
}

// ---------------- K1: 2048 blocks, 8 units -> block-sum -> partials[blk][16] ----------------
__global__ __launch_bounds__(256) void sh_k1(const float* __restrict__ patches,
                                             const float* __restrict__ Y,
                                             float* __restrict__ partials) {
    __shared__ float sh2_lds[8][32][17];
    __shared__ float shl2_lds[8][32][5];
    __shared__ float l2_lds[8][16][4];
    __shared__ float red[8][16];

    const int tid  = threadIdx.x;
    const int wv   = tid >> 6;
    const int lane = tid & 63;
    const int half = lane >> 5;
    const int p    = lane & 31;
    const int u    = wv * 2 + half;
    const int unit = blockIdx.x * 8 + u;

    const float* pp = patches + ((size_t)unit * 32 + p) * 3;
    float x = pp[0], y = pp[1], z = pp[2];
    float dist = sqrtf(x*x + y*y + z*z);
    float inv  = 1.0f / fmaxf(dist, 1e-6f);
    float nx = -x*inv, ny = -y*inv, nz = -z*inv;
    float m[20];
    compute_monoms(nx, ny, nz, m);

#pragma unroll
    for (int i = 0; i < 16; ++i) {
        float acc = 0.f;
#pragma unroll
        for (int j = 0; j < 20; ++j)
            acc = fmaf(Y[i*20 + j], m[j], acc);   // uniform -> s_load
        sh2_lds[u][p][i] = acc * acc;
    }
    float sl[4];
    compute_shells(dist, sl);
#pragma unroll
    for (int s = 0; s < 4; ++s) shl2_lds[u][p][s] = sl[s]*sl[s];
    __syncthreads();

    const int ri = lane >> 2, rs = lane & 3;
    const int u0 = wv*2, u1 = wv*2 + 1;
    float acc0 = 0.f, acc1 = 0.f;
#pragma unroll
    for (int q = 0; q < 32; ++q) {
        acc0 = fmaf(sh2_lds[u0][q][ri], shl2_lds[u0][q][rs], acc0);
        acc1 = fmaf(sh2_lds[u1][q][ri], shl2_lds[u1][q][rs], acc1);
    }
    l2_lds[u0][ri][rs] = acc0;
    l2_lds[u1][ri][rs] = acc1;
    __syncthreads();

    if (lane < 32) {
        const int h2 = lane >> 4;
        const int c  = lane & 15;            // c = l*4 + s
        const int l  = c >> 2, s = c & 3;
        const int uu = wv*2 + h2;
        const int start = l*l, cnt = 2*l + 1;
        float acc = 0.f;
        for (int t = 0; t < cnt; ++t) acc += l2_lds[uu][start + t][s];
        red[uu][c] = sqrtf(acc);
    }
    __syncthreads();
    if (tid < 16) {
        float s2 = 0.f;
#pragma unroll
        for (int uu = 0; uu < 8; ++uu) s2 += red[uu][tid];
        partials[blockIdx.x*16 + tid] = s2;   // deterministic, no atomics
    }
}

// ---------------- K2: 128 blocks -> rcp_ws[b*16+c] ----------------
__global__ __launch_bounds__(256) void sh_k2(const float* __restrict__ partials,
                                             float* __restrict__ rcp_ws) {
    __shared__ float red[256];
    const int b = blockIdx.x >> 4;
    const int c = blockIdx.x & 15;
    red[threadIdx.x] = partials[((size_t)(b*256 + threadIdx.x))*16 + c];
    __syncthreads();
    for (int st = 128; st > 0; st >>= 1) {
        if (threadIdx.x < st) red[threadIdx.x] += red[threadIdx.x + st];
        __syncthreads();
    }
    if (threadIdx.x == 0) {
        float meanv = red[0] * (1.0f/2048.0f);
        rcp_ws[blockIdx.x] = 1.0f / fmaxf(meanv, 1e-8f);
    }
}

// ---------------- K3: 8192 blocks x 64 points; 4 execution waves ----------------
__global__ __launch_bounds__(256) void sh_k3(const float* __restrict__ patches,
                                             const float* __restrict__ Y,
                                             const float* __restrict__ rcp_ws,
                                             f32x4* __restrict__ out) {
    __shared__ float mon[64][12];      // [0..2]=n, [4..7]=sl, stride 12
    __shared__ float rcp_lds[16];

    const int tid = threadIdx.x;
    const int blk = blockIdx.x;        // 0..8191, 1024 blocks per batch
    const int bb  = blk >> 10;         // batch

    if (tid < 16) rcp_lds[tid] = rcp_ws[bb*16 + tid];

    // ---- production: threads 0..63 stage point blk*64+tid ----
    if (tid < 64) {
        const size_t ptg = (size_t)blk*64 + tid;
        const float* pp = patches + ptg*3;
        float x = pp[0], y = pp[1], z = pp[2];
        float dist = sqrtf(x*x + y*y + z*z);
        float inv  = 1.0f / fmaxf(dist, 1e-6f);
        float sl[4];
        compute_shells(dist, sl);
        f32x4 n4 = { -x*inv, -y*inv, -z*inv, 0.f };
        f32x4 s4 = { sl[0], sl[1], sl[2], sl[3] };
        *(f32x4*)&mon[tid][0] = n4;
        *(f32x4*)&mon[tid][4] = s4;
    }
    __syncthreads();

    // ---- consumption: lane -> (pgrp, i); dense 1KB wave stores ----
    const int i    = tid & 15;          // output row
    const int pgrp = tid >> 4;          // 0..15

    const float4* Y4 = (const float4*)Y;
    float yr[20];
#pragma unroll
    for (int q = 0; q < 5; ++q) {
        float4 t = Y4[i*5 + q];
        yr[q*4+0]=t.x; yr[q*4+1]=t.y; yr[q*4+2]=t.z; yr[q*4+3]=t.w;
    }
    const int l = (i == 0) ? 0 : ((i < 4) ? 1 : ((i < 9) ? 2 : 3));
    const float rc0=rcp_lds[l*4+0], rc1=rcp_lds[l*4+1], rc2=rcp_lds[l*4+2], rc3=rcp_lds[l*4+3];

#pragma unroll
    for (int it2 = 0; it2 < 4; ++it2) {
        const int r = it2*16 + pgrp;    // staged point row 0..63
        f32x4 n4 = *(const f32x4*)&mon[r][0];
        f32x4 s4 = *(const f32x4*)&mon[r][4];

        float m[20];
        compute_monoms(n4.x, n4.y, n4.z, m);

        float sh = 0.f;
#pragma unroll
        for (int j = 0; j < 20; ++j)
            sh = fmaf(yr[j], m[j], sh);

        const size_t pt = (size_t)blk*64 + r;
        f32x4 o;
        o.x = sh*s4.x*rc0;
        o.y = sh*s4.y*rc1;
        o.z = sh*s4.z*rc2;
        o.w = sh*s4.w*rc3;
        out[pt*16 + i] = o;             // plain store (R16 keeper)
    }
}

extern "C" void kernel_launch(void* const* d_in, const int* in_sizes, int n_in,
                              void* d_out, int out_size, void* d_ws, size_t ws_size,
                              hipStream_t stream) {
    const float* patches = (const float*)d_in[0];   // 8*2048*32*3
    const float* Y       = (const float*)d_in[1];   // 16*20
    f32x4* out4 = (f32x4*)d_out;

    float* partials = (float*)d_ws;                 // 2048*16 floats = 128 KB
    float* rcp_ws   = partials + 2048*16;           // 128 floats

    sh_k1<<<2048, 256, 0, stream>>>(patches, Y, partials);
    sh_k2<<<128, 256, 0, stream>>>(partials, rcp_ws);
    sh_k3<<<8192, 256, 0, stream>>>(patches, Y, rcp_ws, out4);
}

// Round 22
// 37.194 us; speedup vs baseline: 1.1468x; 1.0709x over previous
//
#include <hip/hip_runtime.h>

typedef float f32x4 __attribute__((ext_vector_type(4)));

// out[b][v][p][i][s] = shell[s]*sh[i] / norm[b][l(i)][s]
// B=8 V=2048 P=32 I=16 S=4, monoms=20
// R16 keeper structure + Horner-factored consumption dot (26 inst vs 37/iter).
// k1: EXACT R16 keeper. k3: only the consumption-loop body changed.

__device__ __forceinline__ void compute_monoms(float nx, float ny, float nz, float* m) {
    float zp2 = nz*nz, zp3 = zp2*nz;
    float yp2 = ny*ny, yp3 = yp2*ny;
    float xp2 = nx*nx, xp3 = xp2*nx;
    m[0]=1.0f;  m[1]=nz;       m[2]=zp2;      m[3]=zp3;
    m[4]=ny;    m[5]=ny*nz;    m[6]=ny*zp2;
    m[7]=yp2;   m[8]=yp2*nz;   m[9]=yp3;
    m[10]=nx;   m[11]=nx*nz;   m[12]=nx*zp2;
    m[13]=nx*ny; m[14]=nx*ny*nz; m[15]=nx*yp2;
    m[16]=xp2;  m[17]=xp2*nz;  m[18]=xp2*ny;
    m[19]=xp3;
}

__device__ __forceinline__ void compute_shells(float dist, float* sl) {
    const float B1 = 32.0f/3.0f, B2 = 64.0f/3.0f, B3 = 32.0f;
    const float C1 = -16.0f/9.0f, C2 = -64.0f/9.0f, C3 = -16.0f;
    float nd2 = -16.0f * dist * dist;
    sl[0] = __expf(nd2);
    sl[1] = __expf(fmaf(B1, dist, nd2 + C1));
    sl[2] = __expf(fmaf(B2, dist, nd2 + C2));
    sl[3] = __expf(fmaf(B3, dist, nd2 + C3));
    float den = sl[0] + sl[1] + sl[2] + sl[3];
    float r = 1.0f / fmaxf(den, 1e-6f);
    float mask = (dist <= 1.0f) ? r : 0.0f;
#pragma unroll
    for (int s = 0; s < 4; ++s) sl[s] *= mask;
}

// ---------------- K1: 2048 blocks, 8 units -> block-sum -> partials[blk][16] ----------------
__global__ __launch_bounds__(256) void sh_k1(const float* __restrict__ patches,
                                             const float* __restrict__ Y,
                                             float* __restrict__ partials) {
    __shared__ float sh2_lds[8][32][17];
    __shared__ float shl2_lds[8][32][5];
    __shared__ float l2_lds[8][16][4];
    __shared__ float red[8][16];

    const int tid  = threadIdx.x;
    const int wv   = tid >> 6;
    const int lane = tid & 63;
    const int half = lane >> 5;
    const int p    = lane & 31;
    const int u    = wv * 2 + half;
    const int unit = blockIdx.x * 8 + u;

    const float* pp = patches + ((size_t)unit * 32 + p) * 3;
    float x = pp[0], y = pp[1], z = pp[2];
    float dist = sqrtf(x*x + y*y + z*z);
    float inv  = 1.0f / fmaxf(dist, 1e-6f);
    float nx = -x*inv, ny = -y*inv, nz = -z*inv;
    float m[20];
    compute_monoms(nx, ny, nz, m);

#pragma unroll
    for (int i = 0; i < 16; ++i) {
        float acc = 0.f;
#pragma unroll
        for (int j = 0; j < 20; ++j)
            acc = fmaf(Y[i*20 + j], m[j], acc);   // uniform -> s_load
        sh2_lds[u][p][i] = acc * acc;
    }
    float sl[4];
    compute_shells(dist, sl);
#pragma unroll
    for (int s = 0; s < 4; ++s) shl2_lds[u][p][s] = sl[s]*sl[s];
    __syncthreads();

    const int ri = lane >> 2, rs = lane & 3;
    const int u0 = wv*2, u1 = wv*2 + 1;
    float acc0 = 0.f, acc1 = 0.f;
#pragma unroll
    for (int q = 0; q < 32; ++q) {
        acc0 = fmaf(sh2_lds[u0][q][ri], shl2_lds[u0][q][rs], acc0);
        acc1 = fmaf(sh2_lds[u1][q][ri], shl2_lds[u1][q][rs], acc1);
    }
    l2_lds[u0][ri][rs] = acc0;
    l2_lds[u1][ri][rs] = acc1;
    __syncthreads();

    if (lane < 32) {
        const int h2 = lane >> 4;
        const int c  = lane & 15;            // c = l*4 + s
        const int l  = c >> 2, s = c & 3;
        const int uu = wv*2 + h2;
        const int start = l*l, cnt = 2*l + 1;
        float acc = 0.f;
        for (int t = 0; t < cnt; ++t) acc += l2_lds[uu][start + t][s];
        red[uu][c] = sqrtf(acc);
    }
    __syncthreads();
    if (tid < 16) {
        float s2 = 0.f;
#pragma unroll
        for (int uu = 0; uu < 8; ++uu) s2 += red[uu][tid];
        partials[blockIdx.x*16 + tid] = s2;   // deterministic, no atomics
    }
}

// ---------------- K3: R16 structure, Horner-factored consumption ----------------
__global__ __launch_bounds__(256) void sh_k3(const float* __restrict__ patches,
                                             const float* __restrict__ Y,
                                             const float* __restrict__ partials,
                                             f32x4* __restrict__ out) {
    __shared__ float mon[256][12];     // [0..2]=n, [4..7]=sl, stride 12
    __shared__ float pr[16][17];
    __shared__ float rcp_lds[16];

    const int tid = threadIdx.x;
    const int blk = blockIdx.x;        // 0..2047, 256 blocks per batch
    const int bb  = blk >> 8;          // batch

    const int ch = tid & 15, r0 = tid >> 4;
    float pl[16];
#pragma unroll
    for (int r = 0; r < 16; ++r)
        pl[r] = partials[((size_t)bb*256 + r0 + r*16)*16 + ch];

    {
        const size_t ptg = (size_t)blk*256 + tid;
        const float* pp = patches + ptg*3;
        float x = pp[0], y = pp[1], z = pp[2];
        float dist = sqrtf(x*x + y*y + z*z);
        float inv  = 1.0f / fmaxf(dist, 1e-6f);
        float sl[4];
        compute_shells(dist, sl);
        f32x4 n4 = { -x*inv, -y*inv, -z*inv, 0.f };
        f32x4 s4 = { sl[0], sl[1], sl[2], sl[3] };
        *(f32x4*)&mon[tid][0] = n4;
        *(f32x4*)&mon[tid][4] = s4;
    }
    {
        float a = 0.f;
#pragma unroll
        for (int r = 0; r < 16; ++r) a += pl[r];
        pr[r0][ch] = a;
    }
    __syncthreads();
    if (tid < 16) {
        float s = 0.f;
#pragma unroll
        for (int r = 0; r < 16; ++r) s += pr[r][tid];
        float meanv = s * (1.0f/2048.0f);
        rcp_lds[tid] = 1.0f / fmaxf(meanv, 1e-8f);
    }
    __syncthreads();

    const int i    = tid & 15;
    const int pgrp = tid >> 4;

    const float4* Y4 = (const float4*)Y;
    float yr[20];
#pragma unroll
    for (int q = 0; q < 5; ++q) {
        float4 t = Y4[i*5 + q];
        yr[q*4+0]=t.x; yr[q*4+1]=t.y; yr[q*4+2]=t.z; yr[q*4+3]=t.w;
    }
    const int l = (i == 0) ? 0 : ((i < 4) ? 1 : ((i < 9) ? 2 : 3));
    const float rc0=rcp_lds[l*4+0], rc1=rcp_lds[l*4+1], rc2=rcp_lds[l*4+2], rc3=rcp_lds[l*4+3];

#pragma unroll 2
    for (int it2 = 0; it2 < 16; ++it2) {
        const int r = it2*16 + pgrp;
        f32x4 n4 = *(const f32x4*)&mon[r][0];
        f32x4 s4 = *(const f32x4*)&mon[r][4];
        const float nx = n4.x, ny = n4.y, nz = n4.z;

        // Horner over powers of nx: 7 mul + 19 FMA (was 17 build + 20 FMA)
        float zp2 = nz*nz, yp2 = ny*ny;
        float zp3 = zp2*nz, yp3 = yp2*ny;
        float ynz = ny*nz, y2nz = yp2*nz, ynz2 = ny*zp2;

        float p0 = fmaf(yr[1], nz, yr[0]);
        p0 = fmaf(yr[2], zp2,  p0);
        p0 = fmaf(yr[3], zp3,  p0);
        p0 = fmaf(yr[4], ny,   p0);
        p0 = fmaf(yr[5], ynz,  p0);
        p0 = fmaf(yr[6], ynz2, p0);
        p0 = fmaf(yr[7], yp2,  p0);
        p0 = fmaf(yr[8], y2nz, p0);
        p0 = fmaf(yr[9], yp3,  p0);

        float p1 = fmaf(yr[11], nz,  yr[10]);
        p1 = fmaf(yr[12], zp2, p1);
        p1 = fmaf(yr[13], ny,  p1);
        p1 = fmaf(yr[14], ynz, p1);
        p1 = fmaf(yr[15], yp2, p1);

        float p2 = fmaf(yr[17], nz, yr[16]);
        p2 = fmaf(yr[18], ny, p2);

        float sh = fmaf(yr[19], nx, p2);
        sh = fmaf(nx, sh, p1);
        sh = fmaf(nx, sh, p0);

        const size_t pt = (size_t)blk*256 + r;
        f32x4 o;
        o.x = sh*s4.x*rc0;
        o.y = sh*s4.y*rc1;
        o.z = sh*s4.z*rc2;
        o.w = sh*s4.w*rc3;
        out[pt*16 + i] = o;             // plain store (R16 keeper)
    }
}

extern "C" void kernel_launch(void* const* d_in, const int* in_sizes, int n_in,
                              void* d_out, int out_size, void* d_ws, size_t ws_size,
                              hipStream_t stream) {
    const float* patches = (const float*)d_in[0];   // 8*2048*32*3
    const float* Y       = (const float*)d_in[1];   // 16*20
    f32x4* out4 = (f32x4*)d_out;

    float* partials = (float*)d_ws;                 // 2048*16 floats = 128 KB

    sh_k1<<<2048, 256, 0, stream>>>(patches, Y, partials);
    sh_k3<<<2048, 256, 0, stream>>>(patches, Y, partials, out4);
}

// Round 23
// 37.067 us; speedup vs baseline: 1.1507x; 1.0034x over previous
//
#include <hip/hip_runtime.h>

typedef float f32x4 __attribute__((ext_vector_type(4)));

// out[b][v][p][i][s] = shell[s]*sh[i] / norm[b][l(i)][s]
// B=8 V=2048 P=32 I=16 S=4, monoms=20
// R16 keeper structure + Horner-factored consumption dot (26 inst vs 37/iter).
// k1: EXACT R16 keeper. k3: only the consumption-loop body changed.

__device__ __forceinline__ void compute_monoms(float nx, float ny, float nz, float* m) {
    float zp2 = nz*nz, zp3 = zp2*nz;
    float yp2 = ny*ny, yp3 = yp2*ny;
    float xp2 = nx*nx, xp3 = xp2*nx;
    m[0]=1.0f;  m[1]=nz;       m[2]=zp2;      m[3]=zp3;
    m[4]=ny;    m[5]=ny*nz;    m[6]=ny*zp2;
    m[7]=yp2;   m[8]=yp2*nz;   m[9]=yp3;
    m[10]=nx;   m[11]=nx*nz;   m[12]=nx*zp2;
    m[13]=nx*ny; m[14]=nx*ny*nz; m[15]=nx*yp2;
    m[16]=xp2;  m[17]=xp2*nz;  m[18]=xp2*ny;
    m[19]=xp3;
}

__device__ __forceinline__ void compute_shells(float dist, float* sl) {
    const float B1 = 32.0f/3.0f, B2 = 64.0f/3.0f, B3 = 32.0f;
    const float C1 = -16.0f/9.0f, C2 = -64.0f/9.0f, C3 = -16.0f;
    float nd2 = -16.0f * dist * dist;
    sl[0] = __expf(nd2);
    sl[1] = __expf(fmaf(B1, dist, nd2 + C1));
    sl[2] = __expf(fmaf(B2, dist, nd2 + C2));
    sl[3] = __expf(fmaf(B3, dist, nd2 + C3));
    float den = sl[0] + sl[1] + sl[2] + sl[3];
    float r = 1.0f / fmaxf(den, 1e-6f);
    float mask = (dist <= 1.0f) ? r : 0.0f;
#pragma unroll
    for (int s = 0; s < 4; ++s) sl[s] *= mask;
}

// ---------------- K1: 2048 blocks, 8 units -> block-sum -> partials[blk][16] ----------------
__global__ __launch_bounds__(256) void sh_k1(const float* __restrict__ patches,
                                             const float* __restrict__ Y,
                                             float* __restrict__ partials) {
    __shared__ float sh2_lds[8][32][17];
    __shared__ float shl2_lds[8][32][5];
    __shared__ float l2_lds[8][16][4];
    __shared__ float red[8][16];

    const int tid  = threadIdx.x;
    const int wv   = tid >> 6;
    const int lane = tid & 63;
    const int half = lane >> 5;
    const int p    = lane & 31;
    const int u    = wv * 2 + half;
    const int unit = blockIdx.x * 8 + u;

    const float* pp = patches + ((size_t)unit * 32 + p) * 3;
    float x = pp[0], y = pp[1], z = pp[2];
    float dist = sqrtf(x*x + y*y + z*z);
    float inv  = 1.0f / fmaxf(dist, 1e-6f);
    float nx = -x*inv, ny = -y*inv, nz = -z*inv;
    float m[20];
    compute_monoms(nx, ny, nz, m);

#pragma unroll
    for (int i = 0; i < 16; ++i) {
        float acc = 0.f;
#pragma unroll
        for (int j = 0; j < 20; ++j)
            acc = fmaf(Y[i*20 + j], m[j], acc);   // uniform -> s_load
        sh2_lds[u][p][i] = acc * acc;
    }
    float sl[4];
    compute_shells(dist, sl);
#pragma unroll
    for (int s = 0; s < 4; ++s) shl2_lds[u][p][s] = sl[s]*sl[s];
    __syncthreads();

    const int ri = lane >> 2, rs = lane & 3;
    const int u0 = wv*2, u1 = wv*2 + 1;
    float acc0 = 0.f, acc1 = 0.f;
#pragma unroll
    for (int q = 0; q < 32; ++q) {
        acc0 = fmaf(sh2_lds[u0][q][ri], shl2_lds[u0][q][rs], acc0);
        acc1 = fmaf(sh2_lds[u1][q][ri], shl2_lds[u1][q][rs], acc1);
    }
    l2_lds[u0][ri][rs] = acc0;
    l2_lds[u1][ri][rs] = acc1;
    __syncthreads();

    if (lane < 32) {
        const int h2 = lane >> 4;
        const int c  = lane & 15;            // c = l*4 + s
        const int l  = c >> 2, s = c & 3;
        const int uu = wv*2 + h2;
        const int start = l*l, cnt = 2*l + 1;
        float acc = 0.f;
        for (int t = 0; t < cnt; ++t) acc += l2_lds[uu][start + t][s];
        red[uu][c] = sqrtf(acc);
    }
    __syncthreads();
    if (tid < 16) {
        float s2 = 0.f;
#pragma unroll
        for (int uu = 0; uu < 8; ++uu) s2 += red[uu][tid];
        partials[blockIdx.x*16 + tid] = s2;   // deterministic, no atomics
    }
}

// ---------------- K3: R16 structure, Horner-factored consumption ----------------
__global__ __launch_bounds__(256) void sh_k3(const float* __restrict__ patches,
                                             const float* __restrict__ Y,
                                             const float* __restrict__ partials,
                                             f32x4* __restrict__ out) {
    __shared__ float mon[256][12];     // [0..2]=n, [4..7]=sl, stride 12
    __shared__ float pr[16][17];
    __shared__ float rcp_lds[16];

    const int tid = threadIdx.x;
    const int blk = blockIdx.x;        // 0..2047, 256 blocks per batch
    const int bb  = blk >> 8;          // batch

    const int ch = tid & 15, r0 = tid >> 4;
    float pl[16];
#pragma unroll
    for (int r = 0; r < 16; ++r)
        pl[r] = partials[((size_t)bb*256 + r0 + r*16)*16 + ch];

    {
        const size_t ptg = (size_t)blk*256 + tid;
        const float* pp = patches + ptg*3;
        float x = pp[0], y = pp[1], z = pp[2];
        float dist = sqrtf(x*x + y*y + z*z);
        float inv  = 1.0f / fmaxf(dist, 1e-6f);
        float sl[4];
        compute_shells(dist, sl);
        f32x4 n4 = { -x*inv, -y*inv, -z*inv, 0.f };
        f32x4 s4 = { sl[0], sl[1], sl[2], sl[3] };
        *(f32x4*)&mon[tid][0] = n4;
        *(f32x4*)&mon[tid][4] = s4;
    }
    {
        float a = 0.f;
#pragma unroll
        for (int r = 0; r < 16; ++r) a += pl[r];
        pr[r0][ch] = a;
    }
    __syncthreads();
    if (tid < 16) {
        float s = 0.f;
#pragma unroll
        for (int r = 0; r < 16; ++r) s += pr[r][tid];
        float meanv = s * (1.0f/2048.0f);
        rcp_lds[tid] = 1.0f / fmaxf(meanv, 1e-8f);
    }
    __syncthreads();

    const int i    = tid & 15;
    const int pgrp = tid >> 4;

    const float4* Y4 = (const float4*)Y;
    float yr[20];
#pragma unroll
    for (int q = 0; q < 5; ++q) {
        float4 t = Y4[i*5 + q];
        yr[q*4+0]=t.x; yr[q*4+1]=t.y; yr[q*4+2]=t.z; yr[q*4+3]=t.w;
    }
    const int l = (i == 0) ? 0 : ((i < 4) ? 1 : ((i < 9) ? 2 : 3));
    const float rc0=rcp_lds[l*4+0], rc1=rcp_lds[l*4+1], rc2=rcp_lds[l*4+2], rc3=rcp_lds[l*4+3];

#pragma unroll 2
    for (int it2 = 0; it2 < 16; ++it2) {
        const int r = it2*16 + pgrp;
        f32x4 n4 = *(const f32x4*)&mon[r][0];
        f32x4 s4 = *(const f32x4*)&mon[r][4];
        const float nx = n4.x, ny = n4.y, nz = n4.z;

        // Horner over powers of nx: 7 mul + 19 FMA (was 17 build + 20 FMA)
        float zp2 = nz*nz, yp2 = ny*ny;
        float zp3 = zp2*nz, yp3 = yp2*ny;
        float ynz = ny*nz, y2nz = yp2*nz, ynz2 = ny*zp2;

        float p0 = fmaf(yr[1], nz, yr[0]);
        p0 = fmaf(yr[2], zp2,  p0);
        p0 = fmaf(yr[3], zp3,  p0);
        p0 = fmaf(yr[4], ny,   p0);
        p0 = fmaf(yr[5], ynz,  p0);
        p0 = fmaf(yr[6], ynz2, p0);
        p0 = fmaf(yr[7], yp2,  p0);
        p0 = fmaf(yr[8], y2nz, p0);
        p0 = fmaf(yr[9], yp3,  p0);

        float p1 = fmaf(yr[11], nz,  yr[10]);
        p1 = fmaf(yr[12], zp2, p1);
        p1 = fmaf(yr[13], ny,  p1);
        p1 = fmaf(yr[14], ynz, p1);
        p1 = fmaf(yr[15], yp2, p1);

        float p2 = fmaf(yr[17], nz, yr[16]);
        p2 = fmaf(yr[18], ny, p2);

        float sh = fmaf(yr[19], nx, p2);
        sh = fmaf(nx, sh, p1);
        sh = fmaf(nx, sh, p0);

        const size_t pt = (size_t)blk*256 + r;
        f32x4 o;
        o.x = sh*s4.x*rc0;
        o.y = sh*s4.y*rc1;
        o.z = sh*s4.z*rc2;
        o.w = sh*s4.w*rc3;
        out[pt*16 + i] = o;             // plain store (R16 keeper)
    }
}

extern "C" void kernel_launch(void* const* d_in, const int* in_sizes, int n_in,
                              void* d_out, int out_size, void* d_ws, size_t ws_size,
                              hipStream_t stream) {
    const float* patches = (const float*)d_in[0];   // 8*2048*32*3
    const float* Y       = (const float*)d_in[1];   // 16*20
    f32x4* out4 = (f32x4*)d_out;

    float* partials = (float*)d_ws;                 // 2048*16 floats = 128 KB

    sh_k1<<<2048, 256, 0, stream>>>(patches, Y, partials);
    sh_k3<<<2048, 256, 0, stream>>>(patches, Y, partials, out4);
}